// Round 4
// baseline (477.781 us; speedup 1.0000x reference)
//
#include <hip/hip_runtime.h>

// ---------------------------------------------------------------------------
// TimeMoeAttention: X@Wq/Wk/Wv + bias -> continuous-time RoPE -> causal GQA
// attention -> @Wo.  B=2, S=2048, H=2048, NH=16, NKV=4, HD=128.
// I/O is fp32 (reference dtypes).  Internal compute: bf16 storage + fp32
// accumulation via mfma_f32_16x16x32_bf16.  Final output written fp32.
// ---------------------------------------------------------------------------

#define S_LEN 2048
#define BATCH 2
#define NH    16
#define NKV   4
#define HD    128

typedef float  f32x4  __attribute__((ext_vector_type(4)));
typedef __bf16 bf16x8 __attribute__((ext_vector_type(8)));
typedef unsigned int u32x4 __attribute__((ext_vector_type(4)));

__device__ inline unsigned short f2bf(float f) {
    unsigned u = __builtin_bit_cast(unsigned, f);
    unsigned r = (u + 0x7fffu + ((u >> 16) & 1u)) >> 16;   // RNE
    return (unsigned short)r;
}
__device__ inline float b2f(unsigned short u) {
    unsigned v = ((unsigned)u) << 16;
    return __builtin_bit_cast(float, v);
}

// ---------------------------------------------------------------------------
// fp32 -> bf16 transpose: dst[n][k] = bf16(src[k][n]).  src is R x C fp32,
// dst (at dst_off) is C x R bf16 with leading dim ldd.  block (32,8).
// ---------------------------------------------------------------------------
__global__ void transpose_to_bf16(const float* __restrict__ src,
                                  unsigned short* __restrict__ dst,
                                  int R, int C, long dst_off, int ldd) {
    __shared__ unsigned short t[32][33];
    int bx = blockIdx.x * 32;   // col base (n)
    int by = blockIdx.y * 32;   // row base (k)
    int x = threadIdx.x, y0 = threadIdx.y;
    #pragma unroll
    for (int i = 0; i < 4; i++) {
        int y = y0 + i * 8;
        t[y][x] = f2bf(src[(long)(by + y) * C + bx + x]);
    }
    __syncthreads();
    #pragma unroll
    for (int i = 0; i < 4; i++) {
        int y = y0 + i * 8;
        dst[dst_off + (long)(bx + y) * ldd + by + x] = t[x][y];
    }
}

// ---------------------------------------------------------------------------
// bias concat: [bq | bk | bv] (fp32) -> fp32[3072]
// ---------------------------------------------------------------------------
__global__ void bias_concat(const float* __restrict__ bq,
                            const float* __restrict__ bk,
                            const float* __restrict__ bv,
                            float* __restrict__ out) {
    int i = blockIdx.x * 256 + threadIdx.x;
    if (i < 3072) {
        out[i] = (i < 2048) ? bq[i] : ((i < 2560) ? bk[i - 2048] : bv[i - 2560]);
    }
}

// ---------------------------------------------------------------------------
// GEMM  C[m][n] = sum_k A[m][k] * Bt[n][k]  (+ bias[n]).
// AT = float (convert to bf16 while staging) or ushort (bf16 passthrough).
// CT = float (raw fp32 store) or ushort (bf16 store).
// 128x128 tile, 4 waves in 2x2, each wave 64x64 via 4x4 16x16x32 MFMA frags.
// LDS stride 40 el -> max 2-way bank aliasing (free per m136).
// ---------------------------------------------------------------------------
template <typename AT, typename CT>
__global__ __launch_bounds__(256) void gemm_bt_kernel(
        const AT* __restrict__ A,
        const unsigned short* __restrict__ Bt,
        CT* __restrict__ C,
        const float* __restrict__ bias,
        int K, int lda, int ldb, int ldc) {
    __shared__ __align__(16) unsigned short As[128 * 40];
    __shared__ __align__(16) unsigned short Bs[128 * 40];
    const int tid = threadIdx.x;
    const int wid = tid >> 6, lane = tid & 63, quad = lane >> 4, l16 = lane & 15;
    const int wr = wid >> 1, wc = wid & 1;
    const int m0 = blockIdx.y * 128, n0 = blockIdx.x * 128;

    f32x4 acc[4][4];
    #pragma unroll
    for (int i = 0; i < 4; i++)
        #pragma unroll
        for (int j = 0; j < 4; j++)
            #pragma unroll
            for (int c = 0; c < 4; c++) acc[i][j][c] = 0.f;

    for (int k0 = 0; k0 < K; k0 += 32) {
        #pragma unroll
        for (int p = 0; p < 2; p++) {
            int c = p * 256 + tid;
            int row = c >> 2, c8 = c & 3;
            if constexpr (sizeof(AT) == 4) {
                // fp32 A: load 8 floats, convert to 8 bf16
                const float* ap = (const float*)&A[(long)(m0 + row) * lda + k0 + c8 * 8];
                f32x4 lo = *(const f32x4*)ap;
                f32x4 hi = *(const f32x4*)(ap + 4);
                unsigned short* dp = &As[row * 40 + c8 * 8];
                #pragma unroll
                for (int e = 0; e < 4; e++) { dp[e] = f2bf(lo[e]); dp[4 + e] = f2bf(hi[e]); }
            } else {
                *(u32x4*)&As[row * 40 + c8 * 8] =
                    *(const u32x4*)&A[(long)(m0 + row) * lda + k0 + c8 * 8];
            }
            *(u32x4*)&Bs[row * 40 + c8 * 8] =
                *(const u32x4*)&Bt[(long)(n0 + row) * ldb + k0 + c8 * 8];
        }
        __syncthreads();
        bf16x8 af[4], bfr[4];
        #pragma unroll
        for (int mi = 0; mi < 4; mi++)
            af[mi] = *(const bf16x8*)&As[(wr * 64 + mi * 16 + l16) * 40 + quad * 8];
        #pragma unroll
        for (int ni = 0; ni < 4; ni++)
            bfr[ni] = *(const bf16x8*)&Bs[(wc * 64 + ni * 16 + l16) * 40 + quad * 8];
        #pragma unroll
        for (int mi = 0; mi < 4; mi++)
            #pragma unroll
            for (int ni = 0; ni < 4; ni++)
                acc[mi][ni] = __builtin_amdgcn_mfma_f32_16x16x32_bf16(
                    af[mi], bfr[ni], acc[mi][ni], 0, 0, 0);
        __syncthreads();
    }

    #pragma unroll
    for (int mi = 0; mi < 4; mi++) {
        #pragma unroll
        for (int ni = 0; ni < 4; ni++) {
            int gn = n0 + wc * 64 + ni * 16 + l16;
            float bv_ = bias ? bias[gn] : 0.f;
            #pragma unroll
            for (int r = 0; r < 4; r++) {
                int gm = m0 + wr * 64 + mi * 16 + quad * 4 + r;
                float v = acc[mi][ni][r] + bv_;
                if constexpr (sizeof(CT) == 4) C[(long)gm * ldc + gn] = v;
                else                           C[(long)gm * ldc + gn] = f2bf(v);
            }
        }
    }
}

// ---------------------------------------------------------------------------
// RoPE + layout shuffle.  C1 is [B*S][3072] bf16 (Q|K|V).  One wave per (b,s):
// thread i handles rotation pair (i, i+64) of each head.  time/rope_w fp32.
// Outputs: Qr [B][NH][S][128], Kr [B][NKV][S][128], Vt [B][NKV][128][S] bf16.
// ---------------------------------------------------------------------------
__global__ __launch_bounds__(64) void rope_kernel(
        const unsigned short* __restrict__ c1,
        const float* __restrict__ timev,
        const float* __restrict__ rope_w,
        unsigned short* __restrict__ Qr,
        unsigned short* __restrict__ Kr,
        unsigned short* __restrict__ Vt) {
    int s = blockIdx.x, b = blockIdx.y;
    int i = threadIdx.x;                      // 0..63
    int m = b * S_LEN + s;
    float t = timev[m];
    float inv = powf(10000.f, -(float)i / 64.f);
    float w = rope_w[i];
    float f = t * inv * w;
    float cs = cosf(f), sn = sinf(f);

    #pragma unroll
    for (int h = 0; h < NH; h++) {
        int base = m * 3072 + h * 128;
        float x1 = b2f(c1[base + i]), x2 = b2f(c1[base + 64 + i]);
        int ob = ((b * NH + h) * S_LEN + s) * 128;
        Qr[ob + i]      = f2bf(x1 * cs - x2 * sn);
        Qr[ob + 64 + i] = f2bf(x2 * cs + x1 * sn);
    }
    #pragma unroll
    for (int h = 0; h < NKV; h++) {
        int base = m * 3072 + 2048 + h * 128;
        float x1 = b2f(c1[base + i]), x2 = b2f(c1[base + 64 + i]);
        int ob = ((b * NKV + h) * S_LEN + s) * 128;
        Kr[ob + i]      = f2bf(x1 * cs - x2 * sn);
        Kr[ob + 64 + i] = f2bf(x2 * cs + x1 * sn);
        int vbase = m * 3072 + 2560 + h * 128;
        int vtb = (b * NKV + h) * 128 * S_LEN;
        Vt[vtb + i * S_LEN + s]        = c1[vbase + i];
        Vt[vtb + (64 + i) * S_LEN + s] = c1[vbase + 64 + i];
    }
}

// ---------------------------------------------------------------------------
// Causal flash attention with GQA.  Grid (S/64, NH, B), 256 threads (4 waves).
// Each wave owns 16 query rows; KV tiles of 64.  QK^T and PV via MFMA; online
// softmax with 16-lane xor-shuffle reductions; P goes C-layout -> LDS ->
// A-layout.  Finite mask (-3e38): no inf arithmetic -> NaN impossible.
// ---------------------------------------------------------------------------
__global__ __launch_bounds__(256) void attn_kernel(
        const unsigned short* __restrict__ Qr,
        const unsigned short* __restrict__ Kr,
        const unsigned short* __restrict__ Vt,
        unsigned short* __restrict__ Out) {
    __shared__ __align__(16) unsigned short Ks[64 * 136];
    __shared__ __align__(16) unsigned short Vs[128 * 72];
    __shared__ __align__(16) unsigned short Ps[4][16 * 72];

    const int qt = blockIdx.x, h = blockIdx.y, b = blockIdx.z;
    const int tid = threadIdx.x, w = tid >> 6, lane = tid & 63;
    const int quad = lane >> 4, l16 = lane & 15;
    const int hk = h >> 2;   // GQA: head h uses kv head h/4
    const unsigned short* Qb = Qr + (b * NH + h) * S_LEN * 128;
    const unsigned short* Kb = Kr + (b * NKV + hk) * S_LEN * 128;
    const unsigned short* Vb = Vt + (b * NKV + hk) * 128 * S_LEN;
    const int q0 = qt * 64;
    const float scale = 0.08838834764831845f;   // 1/sqrt(128)
    const float MASK_MIN = -3.0e38f;

    bf16x8 qf[4];
    #pragma unroll
    for (int kc = 0; kc < 4; kc++)
        qf[kc] = *(const bf16x8*)&Qb[(q0 + w * 16 + l16) * 128 + kc * 32 + quad * 8];

    f32x4 o[8];
    float mr[4], lr[4];
    #pragma unroll
    for (int db = 0; db < 8; db++)
        #pragma unroll
        for (int c = 0; c < 4; c++) o[db][c] = 0.f;
    #pragma unroll
    for (int r = 0; r < 4; r++) { mr[r] = MASK_MIN; lr[r] = 0.f; }

    for (int kt = 0; kt <= qt; kt++) {
        const int k0 = kt * 64;
        __syncthreads();    // prior PV must finish before K/V LDS overwrite
        #pragma unroll
        for (int p = 0; p < 4; p++) {
            int c = p * 256 + tid;
            {   // K tile [64][128] -> Ks (stride 136)
                int row = c >> 4, c8 = c & 15;
                *(u32x4*)&Ks[row * 136 + c8 * 8] =
                    *(const u32x4*)&Kb[k0 * 128 + c * 8];
            }
            {   // V^T tile [128][64] -> Vs (stride 72)
                int row = c >> 3, c8 = c & 7;
                *(u32x4*)&Vs[row * 72 + c8 * 8] =
                    *(const u32x4*)&Vb[row * S_LEN + k0 + c8 * 8];
            }
        }
        __syncthreads();

        // ---- scores = Q K^T ----
        f32x4 sc[4];
        #pragma unroll
        for (int nb = 0; nb < 4; nb++) {
            #pragma unroll
            for (int c = 0; c < 4; c++) sc[nb][c] = 0.f;
            #pragma unroll
            for (int kc = 0; kc < 4; kc++) {
                bf16x8 kf = *(const bf16x8*)&Ks[(nb * 16 + l16) * 136 + kc * 32 + quad * 8];
                sc[nb] = __builtin_amdgcn_mfma_f32_16x16x32_bf16(qf[kc], kf, sc[nb], 0, 0, 0);
            }
        }
        // ---- scale + causal mask ----
        #pragma unroll
        for (int nb = 0; nb < 4; nb++) {
            int kj = k0 + nb * 16 + l16;
            #pragma unroll
            for (int r = 0; r < 4; r++) {
                int qi = q0 + w * 16 + quad * 4 + r;
                float v = sc[nb][r] * scale;
                sc[nb][r] = (kj > qi) ? MASK_MIN : v;
            }
        }
        // ---- online softmax (row values live across 16 lanes) ----
        float alpha[4];
        #pragma unroll
        for (int r = 0; r < 4; r++) {
            float tm = fmaxf(fmaxf(sc[0][r], sc[1][r]), fmaxf(sc[2][r], sc[3][r]));
            #pragma unroll
            for (int off = 1; off < 16; off <<= 1) tm = fmaxf(tm, __shfl_xor(tm, off));
            float mn = fmaxf(mr[r], tm);
            alpha[r] = __expf(mr[r] - mn);
            mr[r] = mn;
            float rs = 0.f;
            #pragma unroll
            for (int nb = 0; nb < 4; nb++) {
                float p = __expf(sc[nb][r] - mn);
                rs += p;
                Ps[w][(quad * 4 + r) * 72 + nb * 16 + l16] = f2bf(p);
            }
            #pragma unroll
            for (int off = 1; off < 16; off <<= 1) rs += __shfl_xor(rs, off);
            lr[r] = lr[r] * alpha[r] + rs;
            #pragma unroll
            for (int db = 0; db < 8; db++) o[db][r] *= alpha[r];
        }
        __syncthreads();    // Ps/Vs ordering across waves

        // ---- O += P V ----
        #pragma unroll
        for (int kk = 0; kk < 2; kk++) {
            bf16x8 pf = *(const bf16x8*)&Ps[w][l16 * 72 + kk * 32 + quad * 8];
            #pragma unroll
            for (int db = 0; db < 8; db++) {
                bf16x8 vf = *(const bf16x8*)&Vs[(db * 16 + l16) * 72 + kk * 32 + quad * 8];
                o[db] = __builtin_amdgcn_mfma_f32_16x16x32_bf16(pf, vf, o[db], 0, 0, 0);
            }
        }
    }

    // ---- epilogue: normalize, write [B][S][NH*128] bf16 ----
    #pragma unroll
    for (int db = 0; db < 8; db++) {
        #pragma unroll
        for (int r = 0; r < 4; r++) {
            int qi = q0 + w * 16 + quad * 4 + r;
            float v = o[db][r] / lr[r];
            Out[(b * S_LEN + qi) * 2048 + h * 128 + db * 16 + l16] = f2bf(v);
        }
    }
}

// ---------------------------------------------------------------------------
extern "C" void kernel_launch(void* const* d_in, const int* in_sizes, int n_in,
                              void* d_out, int out_size, void* d_ws, size_t ws_size,
                              hipStream_t stream) {
    const float* X  = (const float*)d_in[0];  // [4096][2048]
    const float* tv = (const float*)d_in[1];  // [2][2048]
    const float* wq = (const float*)d_in[2];  // [2048][2048]
    const float* bq = (const float*)d_in[3];
    const float* wk = (const float*)d_in[4];  // [2048][512]
    const float* bk = (const float*)d_in[5];
    const float* wv = (const float*)d_in[6];  // [2048][512]
    const float* bv = (const float*)d_in[7];
    const float* wo = (const float*)d_in[8];  // [2048][2048]
    const float* rw = (const float*)d_in[9];  // [64]

    // Workspace plan (~63 MB):
    //   Wt  : 12.6 MB  [wq|wk|wv]^T bf16 for gemm1, then REUSED for wo^T
    //   bsf : 12 KB fp32 bias
    //   C1  : 25.2 MB  QKV pre-rope bf16; REUSED as AO after rope
    //   Qr/Kr/Vt : 25.2 MB bf16
    char* ws = (char*)d_ws;
    unsigned short* Wt  = (unsigned short*)ws; ws += 3072L * 2048 * 2;
    float*          bsf = (float*)ws;          ws += 3072L * 4;
    unsigned short* C1  = (unsigned short*)ws; ws += 4096L * 3072 * 2;
    unsigned short* Qr  = (unsigned short*)ws; ws += (long)BATCH * NH  * S_LEN * 128 * 2;
    unsigned short* Kr  = (unsigned short*)ws; ws += (long)BATCH * NKV * S_LEN * 128 * 2;
    unsigned short* Vt  = (unsigned short*)ws; ws += (long)BATCH * NKV * 128 * S_LEN * 2;
    unsigned short* AO  = C1;   // alias: C1 dead after rope_kernel

    dim3 tb(32, 8);
    transpose_to_bf16<<<dim3(64, 64), tb, 0, stream>>>(wq, Wt, 2048, 2048, 0L, 2048);
    transpose_to_bf16<<<dim3(16, 64), tb, 0, stream>>>(wk, Wt, 2048, 512, 2048L * 2048, 2048);
    transpose_to_bf16<<<dim3(16, 64), tb, 0, stream>>>(wv, Wt, 2048, 512, 2560L * 2048, 2048);
    bias_concat<<<12, 256, 0, stream>>>(bq, bk, bv, bsf);

    // QKV projection: [4096][2048] x [3072][2048]^T -> [4096][3072] bf16
    gemm_bt_kernel<float, unsigned short><<<dim3(24, 32), 256, 0, stream>>>(
        X, Wt, C1, bsf, 2048, 2048, 2048, 3072);
    rope_kernel<<<dim3(S_LEN, BATCH), 64, 0, stream>>>(C1, tv, rw, Qr, Kr, Vt);
    // Wt is dead (gemm1 done, stream-ordered): reuse for wo^T.
    transpose_to_bf16<<<dim3(64, 64), tb, 0, stream>>>(wo, Wt, 2048, 2048, 0L, 2048);
    attn_kernel<<<dim3(S_LEN / 64, NH, BATCH), 256, 0, stream>>>(Qr, Kr, Vt, AO);
    // Output projection: [4096][2048] bf16 x [2048][2048]^T -> d_out fp32
    gemm_bt_kernel<unsigned short, float><<<dim3(16, 32), 256, 0, stream>>>(
        AO, Wt, (float*)d_out, nullptr, 2048, 2048, 2048, 2048);
}

// Round 5
// 444.540 us; speedup vs baseline: 1.0748x; 1.0748x over previous
//
#include <hip/hip_runtime.h>

// ---------------------------------------------------------------------------
// TimeMoeAttention: X@Wq/Wk/Wv + bias -> continuous-time RoPE -> causal GQA
// attention -> @Wo.  B=2, S=2048, H=2048, NH=16, NKV=4, HD=128.
// I/O fp32; internal bf16 + fp32 MFMA accumulation.
// R5: attn 128-row Q-tiles / 512 thr / paired causal schedule / stride 132|68
//     (4-way max conflicts) / 2 barriers per tile / base-2 softmax;
//     GEMMs use global_load_lds width-16 (m97 structure) with bf16 A.
// ---------------------------------------------------------------------------

#define S_LEN 2048
#define BATCH 2
#define NH    16
#define NKV   4
#define HD    128

typedef float  f32x4  __attribute__((ext_vector_type(4)));
typedef __bf16 bf16x8 __attribute__((ext_vector_type(8)));
typedef unsigned int u32x4 __attribute__((ext_vector_type(4)));

__device__ inline unsigned short f2bf(float f) {
    unsigned u = __builtin_bit_cast(unsigned, f);
    unsigned r = (u + 0x7fffu + ((u >> 16) & 1u)) >> 16;   // RNE
    return (unsigned short)r;
}
__device__ inline float b2f(unsigned short u) {
    unsigned v = ((unsigned)u) << 16;
    return __builtin_bit_cast(float, v);
}

// async global->LDS, 16 bytes per lane (dest = wave-uniform base + lane*16)
__device__ inline void gload_lds16(const void* g, void* l) {
    __builtin_amdgcn_global_load_lds(
        (const __attribute__((address_space(1))) unsigned int*)g,
        (__attribute__((address_space(3))) unsigned int*)l, 16, 0, 0);
}

// ---------------------------------------------------------------------------
// fp32 -> bf16 row-major convert (vectorized 8 el/thread)
// ---------------------------------------------------------------------------
__global__ void f32_to_bf16_kernel(const float* __restrict__ src,
                                   unsigned short* __restrict__ dst, long n) {
    long i = ((long)blockIdx.x * 256 + threadIdx.x) * 8;
    if (i < n) {
        f32x4 a = *(const f32x4*)&src[i];
        f32x4 b = *(const f32x4*)&src[i + 4];
        u32x4 r;
        r.x = (unsigned)f2bf(a[0]) | ((unsigned)f2bf(a[1]) << 16);
        r.y = (unsigned)f2bf(a[2]) | ((unsigned)f2bf(a[3]) << 16);
        r.z = (unsigned)f2bf(b[0]) | ((unsigned)f2bf(b[1]) << 16);
        r.w = (unsigned)f2bf(b[2]) | ((unsigned)f2bf(b[3]) << 16);
        *(u32x4*)&dst[i] = r;
    }
}

// ---------------------------------------------------------------------------
// fp32 -> bf16 transpose: dst[n][k] = bf16(src[k][n]).
// ---------------------------------------------------------------------------
__global__ void transpose_to_bf16(const float* __restrict__ src,
                                  unsigned short* __restrict__ dst,
                                  int R, int C, long dst_off, int ldd) {
    __shared__ unsigned short t[32][33];
    int bx = blockIdx.x * 32, by = blockIdx.y * 32;
    int x = threadIdx.x, y0 = threadIdx.y;
    #pragma unroll
    for (int i = 0; i < 4; i++) {
        int y = y0 + i * 8;
        t[y][x] = f2bf(src[(long)(by + y) * C + bx + x]);
    }
    __syncthreads();
    #pragma unroll
    for (int i = 0; i < 4; i++) {
        int y = y0 + i * 8;
        dst[dst_off + (long)(bx + y) * ldd + by + x] = t[x][y];
    }
}

// ---------------------------------------------------------------------------
// bias concat: [bq | bk | bv] (fp32) -> fp32[3072]
// ---------------------------------------------------------------------------
__global__ void bias_concat(const float* __restrict__ bq,
                            const float* __restrict__ bk,
                            const float* __restrict__ bv,
                            float* __restrict__ out) {
    int i = blockIdx.x * 256 + threadIdx.x;
    if (i < 3072) {
        out[i] = (i < 2048) ? bq[i] : ((i < 2560) ? bk[i - 2048] : bv[i - 2560]);
    }
}

// ---------------------------------------------------------------------------
// GEMM  C[m][n] = sum_k A[m][k]*Bt[n][k] (+bias).  A,Bt bf16; CT selects
// fp32/bf16 store.  m97 structure: 128x128 tile, BK=32, UNPADDED LDS staged
// via global_load_lds dwordx4 (dest must be lane-contiguous: no padding).
// ---------------------------------------------------------------------------
template <typename CT>
__global__ __launch_bounds__(256) void gemm_bt_async(
        const unsigned short* __restrict__ A,
        const unsigned short* __restrict__ Bt,
        CT* __restrict__ C,
        const float* __restrict__ bias,
        int K, int lda, int ldb, int ldc) {
    __shared__ __align__(16) unsigned short As[128 * 32];
    __shared__ __align__(16) unsigned short Bs[128 * 32];
    const int tid = threadIdx.x;
    const int wid = tid >> 6, lane = tid & 63, quad = lane >> 4, l16 = lane & 15;
    const int wr = wid >> 1, wc = wid & 1;
    const int m0 = blockIdx.y * 128, n0 = blockIdx.x * 128;

    // chunk coords: chunk c covers row c>>2, k-cols (c&3)*8..+7; LDS byte c*16
    const int cA = tid, cB = 256 + tid;
    const int rowA = cA >> 2, colA = (cA & 3) * 8;
    const int rowB = cB >> 2, colB = (cB & 3) * 8;

    f32x4 acc[4][4];
    #pragma unroll
    for (int i = 0; i < 4; i++)
        #pragma unroll
        for (int j = 0; j < 4; j++)
            #pragma unroll
            for (int c = 0; c < 4; c++) acc[i][j][c] = 0.f;

    for (int k0 = 0; k0 < K; k0 += 32) {
        gload_lds16(&A[(long)(m0 + rowA) * lda + k0 + colA], &As[cA * 8]);
        gload_lds16(&A[(long)(m0 + rowB) * lda + k0 + colB], &As[cB * 8]);
        gload_lds16(&Bt[(long)(n0 + rowA) * ldb + k0 + colA], &Bs[cA * 8]);
        gload_lds16(&Bt[(long)(n0 + rowB) * ldb + k0 + colB], &Bs[cB * 8]);
        __syncthreads();   // drains vmcnt (loads landed) + wave sync
        bf16x8 af[4], bfr[4];
        #pragma unroll
        for (int mi = 0; mi < 4; mi++)
            af[mi] = *(const bf16x8*)&As[(wr * 64 + mi * 16 + l16) * 32 + quad * 8];
        #pragma unroll
        for (int ni = 0; ni < 4; ni++)
            bfr[ni] = *(const bf16x8*)&Bs[(wc * 64 + ni * 16 + l16) * 32 + quad * 8];
        #pragma unroll
        for (int mi = 0; mi < 4; mi++)
            #pragma unroll
            for (int ni = 0; ni < 4; ni++)
                acc[mi][ni] = __builtin_amdgcn_mfma_f32_16x16x32_bf16(
                    af[mi], bfr[ni], acc[mi][ni], 0, 0, 0);
        __syncthreads();   // protect LDS before next stage
    }

    #pragma unroll
    for (int mi = 0; mi < 4; mi++) {
        #pragma unroll
        for (int ni = 0; ni < 4; ni++) {
            int gn = n0 + wc * 64 + ni * 16 + l16;
            float bv_ = bias ? bias[gn] : 0.f;
            #pragma unroll
            for (int r = 0; r < 4; r++) {
                int gm = m0 + wr * 64 + mi * 16 + quad * 4 + r;
                float v = acc[mi][ni][r] + bv_;
                if constexpr (sizeof(CT) == 4) C[(long)gm * ldc + gn] = v;
                else                           C[(long)gm * ldc + gn] = f2bf(v);
            }
        }
    }
}

// ---------------------------------------------------------------------------
// RoPE + layout shuffle (unchanged from R4 — verified correct).
// ---------------------------------------------------------------------------
__global__ __launch_bounds__(64) void rope_kernel(
        const unsigned short* __restrict__ c1,
        const float* __restrict__ timev,
        const float* __restrict__ rope_w,
        unsigned short* __restrict__ Qr,
        unsigned short* __restrict__ Kr,
        unsigned short* __restrict__ Vt) {
    int s = blockIdx.x, b = blockIdx.y;
    int i = threadIdx.x;
    int m = b * S_LEN + s;
    float t = timev[m];
    float inv = powf(10000.f, -(float)i / 64.f);
    float w = rope_w[i];
    float f = t * inv * w;
    float cs = cosf(f), sn = sinf(f);

    #pragma unroll
    for (int h = 0; h < NH; h++) {
        int base = m * 3072 + h * 128;
        float x1 = b2f(c1[base + i]), x2 = b2f(c1[base + 64 + i]);
        int ob = ((b * NH + h) * S_LEN + s) * 128;
        Qr[ob + i]      = f2bf(x1 * cs - x2 * sn);
        Qr[ob + 64 + i] = f2bf(x2 * cs + x1 * sn);
    }
    #pragma unroll
    for (int h = 0; h < NKV; h++) {
        int base = m * 3072 + 2048 + h * 128;
        float x1 = b2f(c1[base + i]), x2 = b2f(c1[base + 64 + i]);
        int ob = ((b * NKV + h) * S_LEN + s) * 128;
        Kr[ob + i]      = f2bf(x1 * cs - x2 * sn);
        Kr[ob + 64 + i] = f2bf(x2 * cs + x1 * sn);
        int vbase = m * 3072 + 2560 + h * 128;
        int vtb = (b * NKV + h) * 128 * S_LEN;
        Vt[vtb + i * S_LEN + s]        = c1[vbase + i];
        Vt[vtb + (64 + i) * S_LEN + s] = c1[vbase + 64 + i];
    }
}

// ---------------------------------------------------------------------------
// Causal flash attention, GQA.  Grid (NH, 16, B), 512 threads = 8 waves;
// block owns 128 q rows (wave w: rows q0+16w..+15), KV tiles of 64.
// qt = b ? y : 15-y pairs long+short blocks per CU (balanced makespan).
// Strides 132/68 el (66/34 dw, ==2 mod 32 -> 4-way max conflict).
// 2 barriers/tile; waves skip compute on fully-masked tiles; per-element
// mask only on diagonal tiles; base-2 online softmax.
// ---------------------------------------------------------------------------
__global__ __launch_bounds__(512) void attn_kernel(
        const unsigned short* __restrict__ Qr,
        const unsigned short* __restrict__ Kr,
        const unsigned short* __restrict__ Vt,
        unsigned short* __restrict__ Out) {
    __shared__ __align__(16) unsigned short Ks[64 * 132];
    __shared__ __align__(16) unsigned short Vs[128 * 68];
    __shared__ __align__(16) unsigned short Ps[8][16 * 68];

    const int h = blockIdx.x, b = blockIdx.z;
    const int qt = b ? blockIdx.y : (int)(gridDim.y - 1 - blockIdx.y);
    const int tid = threadIdx.x, w = tid >> 6, lane = tid & 63;
    const int quad = lane >> 4, l16 = lane & 15;
    const int hk = h >> 2;
    const unsigned short* Qb = Qr + (long)((b * NH + h) * S_LEN) * HD;
    const unsigned short* Kb = Kr + (long)((b * NKV + hk) * S_LEN) * HD;
    const unsigned short* Vb = Vt + (long)((b * NKV + hk) * HD) * S_LEN;
    const int q0 = qt * 128;
    const int qw = q0 + w * 16;             // this wave's first q row
    const float sl2 = 0.08838834764831845f * 1.4426950408889634f; // scale*log2(e)
    const float MASK_MIN = -3.0e38f;

    bf16x8 qf[4];
    #pragma unroll
    for (int kc = 0; kc < 4; kc++)
        qf[kc] = *(const bf16x8*)&Qb[(long)(qw + l16) * HD + kc * 32 + quad * 8];

    f32x4 o[8];
    float mr[4], lr[4];
    #pragma unroll
    for (int db = 0; db < 8; db++)
        #pragma unroll
        for (int c = 0; c < 4; c++) o[db][c] = 0.f;
    #pragma unroll
    for (int r = 0; r < 4; r++) { mr[r] = MASK_MIN; lr[r] = 0.f; }

    const int nkt = 2 * qt + 2;
    for (int kt = 0; kt < nkt; kt++) {
        const int k0 = kt * 64;
        __syncthreads();    // prior tile's reads done before LDS overwrite
        #pragma unroll
        for (int p = 0; p < 2; p++) {
            int c = p * 512 + tid;
            {   // K tile [64][128] -> Ks (stride 132)
                int row = c >> 4, c8 = c & 15;
                *(u32x4*)&Ks[row * 132 + c8 * 8] =
                    *(const u32x4*)&Kb[(long)k0 * HD + c * 8];
            }
            {   // V^T tile [128][64] -> Vs (stride 68)
                int row = c >> 3, c8 = c & 7;
                *(u32x4*)&Vs[row * 68 + c8 * 8] =
                    *(const u32x4*)&Vb[(long)row * S_LEN + k0 + c8 * 8];
            }
        }
        __syncthreads();

        if (k0 > qw + 15) continue;         // tile fully masked for this wave

        // ---- scores = Q K^T (base-2 logits) ----
        f32x4 sc[4];
        #pragma unroll
        for (int nb = 0; nb < 4; nb++) {
            #pragma unroll
            for (int c = 0; c < 4; c++) sc[nb][c] = 0.f;
            #pragma unroll
            for (int kc = 0; kc < 4; kc++) {
                bf16x8 kf = *(const bf16x8*)&Ks[(nb * 16 + l16) * 132 + kc * 32 + quad * 8];
                sc[nb] = __builtin_amdgcn_mfma_f32_16x16x32_bf16(qf[kc], kf, sc[nb], 0, 0, 0);
            }
        }
        if (k0 + 63 > qw) {                 // diagonal tile: apply causal mask
            #pragma unroll
            for (int nb = 0; nb < 4; nb++) {
                int kj = k0 + nb * 16 + l16;
                #pragma unroll
                for (int r = 0; r < 4; r++) {
                    int qi = qw + quad * 4 + r;
                    float v = sc[nb][r] * sl2;
                    sc[nb][r] = (kj > qi) ? MASK_MIN : v;
                }
            }
        } else {
            #pragma unroll
            for (int nb = 0; nb < 4; nb++)
                #pragma unroll
                for (int r = 0; r < 4; r++) sc[nb][r] *= sl2;
        }
        // ---- online softmax (rows live across 16 lanes) ----
        float alpha[4];
        #pragma unroll
        for (int r = 0; r < 4; r++) {
            float tm = fmaxf(fmaxf(sc[0][r], sc[1][r]), fmaxf(sc[2][r], sc[3][r]));
            #pragma unroll
            for (int off = 1; off < 16; off <<= 1) tm = fmaxf(tm, __shfl_xor(tm, off));
            float mn = fmaxf(mr[r], tm);
            alpha[r] = exp2f(mr[r] - mn);
            mr[r] = mn;
            float rs = 0.f;
            #pragma unroll
            for (int nb = 0; nb < 4; nb++) {
                float p = exp2f(sc[nb][r] - mn);
                rs += p;
                Ps[w][(quad * 4 + r) * 68 + nb * 16 + l16] = f2bf(p);
            }
            #pragma unroll
            for (int off = 1; off < 16; off <<= 1) rs += __shfl_xor(rs, off);
            lr[r] = lr[r] * alpha[r] + rs;
            #pragma unroll
            for (int db = 0; db < 8; db++) o[db][r] *= alpha[r];
        }
        // (no barrier: Ps[w] is private to wave w; lgkmcnt orders write->read)

        // ---- O += P V ----
        #pragma unroll
        for (int kk = 0; kk < 2; kk++) {
            bf16x8 pf = *(const bf16x8*)&Ps[w][l16 * 68 + kk * 32 + quad * 8];
            #pragma unroll
            for (int db = 0; db < 8; db++) {
                bf16x8 vf = *(const bf16x8*)&Vs[(db * 16 + l16) * 68 + kk * 32 + quad * 8];
                o[db] = __builtin_amdgcn_mfma_f32_16x16x32_bf16(pf, vf, o[db], 0, 0, 0);
            }
        }
    }

    // ---- epilogue: normalize, write [B][S][NH*128] bf16 ----
    #pragma unroll
    for (int db = 0; db < 8; db++) {
        #pragma unroll
        for (int r = 0; r < 4; r++) {
            int qi = qw + quad * 4 + r;
            float v = o[db][r] / lr[r];
            Out[(long)(b * S_LEN + qi) * 2048 + h * 128 + db * 16 + l16] = f2bf(v);
        }
    }
}

// ---------------------------------------------------------------------------
extern "C" void kernel_launch(void* const* d_in, const int* in_sizes, int n_in,
                              void* d_out, int out_size, void* d_ws, size_t ws_size,
                              hipStream_t stream) {
    const float* X  = (const float*)d_in[0];
    const float* tv = (const float*)d_in[1];
    const float* wq = (const float*)d_in[2];
    const float* bq = (const float*)d_in[3];
    const float* wk = (const float*)d_in[4];
    const float* bk = (const float*)d_in[5];
    const float* wv = (const float*)d_in[6];
    const float* bv = (const float*)d_in[7];
    const float* wo = (const float*)d_in[8];
    const float* rw = (const float*)d_in[9];

    // Workspace (~63 MB, unchanged):
    //   Wt  12.6 MB : [wq|wk|wv]^T bf16 -> reused for wo^T after gemm1
    //   bsf 12 KB
    //   C1  25.2 MB : QKV pre-rope bf16 -> reused as AO after rope
    //   R   25.2 MB : Xb (bf16 X, dead after gemm1) overlaid by Qr|Kr|Vt
    char* ws = (char*)d_ws;
    unsigned short* Wt  = (unsigned short*)ws; ws += 3072L * 2048 * 2;
    float*          bsf = (float*)ws;          ws += 3072L * 4;
    unsigned short* C1  = (unsigned short*)ws; ws += 4096L * 3072 * 2;
    unsigned short* Qr  = (unsigned short*)ws; ws += (long)BATCH * NH  * S_LEN * 128 * 2;
    unsigned short* Kr  = (unsigned short*)ws; ws += (long)BATCH * NKV * S_LEN * 128 * 2;
    unsigned short* Vt  = (unsigned short*)ws; ws += (long)BATCH * NKV * 128 * S_LEN * 2;
    unsigned short* Xb  = Qr;   // alias: Xb dead before rope writes Qr
    unsigned short* AO  = C1;   // alias: C1 dead after rope

    dim3 tb(32, 8);
    f32_to_bf16_kernel<<<4096, 256, 0, stream>>>(X, Xb, 4096L * 2048);
    transpose_to_bf16<<<dim3(64, 64), tb, 0, stream>>>(wq, Wt, 2048, 2048, 0L, 2048);
    transpose_to_bf16<<<dim3(16, 64), tb, 0, stream>>>(wk, Wt, 2048, 512, 2048L * 2048, 2048);
    transpose_to_bf16<<<dim3(16, 64), tb, 0, stream>>>(wv, Wt, 2048, 512, 2560L * 2048, 2048);
    bias_concat<<<12, 256, 0, stream>>>(bq, bk, bv, bsf);

    // QKV projection: [4096][2048] x [3072][2048]^T -> [4096][3072] bf16
    gemm_bt_async<unsigned short><<<dim3(24, 32), 256, 0, stream>>>(
        Xb, Wt, C1, bsf, 2048, 2048, 2048, 3072);
    rope_kernel<<<dim3(S_LEN, BATCH), 64, 0, stream>>>(C1, tv, rw, Qr, Kr, Vt);
    transpose_to_bf16<<<dim3(64, 64), tb, 0, stream>>>(wo, Wt, 2048, 2048, 0L, 2048);
    attn_kernel<<<dim3(NH, S_LEN / 128, BATCH), 512, 0, stream>>>(Qr, Kr, Vt, AO);
    // Output projection: [4096][2048] bf16 x [2048][2048]^T -> d_out fp32
    gemm_bt_async<float><<<dim3(16, 32), 256, 0, stream>>>(
        AO, Wt, (float*)d_out, nullptr, 2048, 2048, 2048, 2048);
}

// Round 6
// 357.482 us; speedup vs baseline: 1.3365x; 1.2435x over previous
//
#include <hip/hip_runtime.h>

// ---------------------------------------------------------------------------
// TimeMoeAttention: X@Wq/Wk/Wv + bias -> continuous-time RoPE -> causal GQA
// attention -> @Wo.  B=2, S=2048, H=2048, NH=16, NKV=4, HD=128.
// I/O fp32; internal bf16 + fp32 MFMA accumulation.
// R6: attention restructured as S^T = K Q^T (per-lane softmax rows: 2 shuffles
//     per tile instead of 32), XOR-swizzled global_load_lds K/V staging,
//     __launch_bounds__(512,4) to cap regs at 128 -> 2 blocks/CU.
// ---------------------------------------------------------------------------

#define S_LEN 2048
#define BATCH 2
#define NH    16
#define NKV   4
#define HD    128

typedef float  f32x4  __attribute__((ext_vector_type(4)));
typedef __bf16 bf16x8 __attribute__((ext_vector_type(8)));
typedef unsigned int u32x4 __attribute__((ext_vector_type(4)));
typedef unsigned int u32x2 __attribute__((ext_vector_type(2)));

__device__ inline unsigned short f2bf(float f) {
    unsigned u = __builtin_bit_cast(unsigned, f);
    unsigned r = (u + 0x7fffu + ((u >> 16) & 1u)) >> 16;   // RNE
    return (unsigned short)r;
}
__device__ inline float b2f(unsigned short u) {
    unsigned v = ((unsigned)u) << 16;
    return __builtin_bit_cast(float, v);
}

// async global->LDS, 16 bytes per lane (dest = wave-uniform base + lane*16)
__device__ inline void gload_lds16(const void* g, void* l) {
    __builtin_amdgcn_global_load_lds(
        (const __attribute__((address_space(1))) unsigned int*)g,
        (__attribute__((address_space(3))) unsigned int*)l, 16, 0, 0);
}

// ---------------------------------------------------------------------------
// fp32 -> bf16 row-major convert (vectorized 8 el/thread)
// ---------------------------------------------------------------------------
__global__ void f32_to_bf16_kernel(const float* __restrict__ src,
                                   unsigned short* __restrict__ dst, long n) {
    long i = ((long)blockIdx.x * 256 + threadIdx.x) * 8;
    if (i < n) {
        f32x4 a = *(const f32x4*)&src[i];
        f32x4 b = *(const f32x4*)&src[i + 4];
        u32x4 r;
        r.x = (unsigned)f2bf(a[0]) | ((unsigned)f2bf(a[1]) << 16);
        r.y = (unsigned)f2bf(a[2]) | ((unsigned)f2bf(a[3]) << 16);
        r.z = (unsigned)f2bf(b[0]) | ((unsigned)f2bf(b[1]) << 16);
        r.w = (unsigned)f2bf(b[2]) | ((unsigned)f2bf(b[3]) << 16);
        *(u32x4*)&dst[i] = r;
    }
}

// ---------------------------------------------------------------------------
// fp32 -> bf16 transpose: dst[n][k] = bf16(src[k][n]).
// ---------------------------------------------------------------------------
__global__ void transpose_to_bf16(const float* __restrict__ src,
                                  unsigned short* __restrict__ dst,
                                  int R, int C, long dst_off, int ldd) {
    __shared__ unsigned short t[32][33];
    int bx = blockIdx.x * 32, by = blockIdx.y * 32;
    int x = threadIdx.x, y0 = threadIdx.y;
    #pragma unroll
    for (int i = 0; i < 4; i++) {
        int y = y0 + i * 8;
        t[y][x] = f2bf(src[(long)(by + y) * C + bx + x]);
    }
    __syncthreads();
    #pragma unroll
    for (int i = 0; i < 4; i++) {
        int y = y0 + i * 8;
        dst[dst_off + (long)(bx + y) * ldd + by + x] = t[x][y];
    }
}

// ---------------------------------------------------------------------------
// bias concat: [bq | bk | bv] (fp32) -> fp32[3072]
// ---------------------------------------------------------------------------
__global__ void bias_concat(const float* __restrict__ bq,
                            const float* __restrict__ bk,
                            const float* __restrict__ bv,
                            float* __restrict__ out) {
    int i = blockIdx.x * 256 + threadIdx.x;
    if (i < 3072) {
        out[i] = (i < 2048) ? bq[i] : ((i < 2560) ? bk[i - 2048] : bv[i - 2560]);
    }
}

// ---------------------------------------------------------------------------
// GEMM  C[m][n] = sum_k A[m][k]*Bt[n][k] (+bias).  A,Bt bf16; CT selects
// fp32/bf16 store.  m97 structure (unchanged from R5, known-good).
// ---------------------------------------------------------------------------
template <typename CT>
__global__ __launch_bounds__(256) void gemm_bt_async(
        const unsigned short* __restrict__ A,
        const unsigned short* __restrict__ Bt,
        CT* __restrict__ C,
        const float* __restrict__ bias,
        int K, int lda, int ldb, int ldc) {
    __shared__ __align__(16) unsigned short As[128 * 32];
    __shared__ __align__(16) unsigned short Bs[128 * 32];
    const int tid = threadIdx.x;
    const int wid = tid >> 6, lane = tid & 63, quad = lane >> 4, l16 = lane & 15;
    const int wr = wid >> 1, wc = wid & 1;
    const int m0 = blockIdx.y * 128, n0 = blockIdx.x * 128;

    const int cA = tid, cB = 256 + tid;
    const int rowA = cA >> 2, colA = (cA & 3) * 8;
    const int rowB = cB >> 2, colB = (cB & 3) * 8;

    f32x4 acc[4][4];
    #pragma unroll
    for (int i = 0; i < 4; i++)
        #pragma unroll
        for (int j = 0; j < 4; j++)
            #pragma unroll
            for (int c = 0; c < 4; c++) acc[i][j][c] = 0.f;

    for (int k0 = 0; k0 < K; k0 += 32) {
        gload_lds16(&A[(long)(m0 + rowA) * lda + k0 + colA], &As[cA * 8]);
        gload_lds16(&A[(long)(m0 + rowB) * lda + k0 + colB], &As[cB * 8]);
        gload_lds16(&Bt[(long)(n0 + rowA) * ldb + k0 + colA], &Bs[cA * 8]);
        gload_lds16(&Bt[(long)(n0 + rowB) * ldb + k0 + colB], &Bs[cB * 8]);
        __syncthreads();
        bf16x8 af[4], bfr[4];
        #pragma unroll
        for (int mi = 0; mi < 4; mi++)
            af[mi] = *(const bf16x8*)&As[(wr * 64 + mi * 16 + l16) * 32 + quad * 8];
        #pragma unroll
        for (int ni = 0; ni < 4; ni++)
            bfr[ni] = *(const bf16x8*)&Bs[(wc * 64 + ni * 16 + l16) * 32 + quad * 8];
        #pragma unroll
        for (int mi = 0; mi < 4; mi++)
            #pragma unroll
            for (int ni = 0; ni < 4; ni++)
                acc[mi][ni] = __builtin_amdgcn_mfma_f32_16x16x32_bf16(
                    af[mi], bfr[ni], acc[mi][ni], 0, 0, 0);
        __syncthreads();
    }

    #pragma unroll
    for (int mi = 0; mi < 4; mi++) {
        #pragma unroll
        for (int ni = 0; ni < 4; ni++) {
            int gn = n0 + wc * 64 + ni * 16 + l16;
            float bv_ = bias ? bias[gn] : 0.f;
            #pragma unroll
            for (int r = 0; r < 4; r++) {
                int gm = m0 + wr * 64 + mi * 16 + quad * 4 + r;
                float v = acc[mi][ni][r] + bv_;
                if constexpr (sizeof(CT) == 4) C[(long)gm * ldc + gn] = v;
                else                           C[(long)gm * ldc + gn] = f2bf(v);
            }
        }
    }
}

// ---------------------------------------------------------------------------
// RoPE + layout shuffle (unchanged, known-good).
// ---------------------------------------------------------------------------
__global__ __launch_bounds__(64) void rope_kernel(
        const unsigned short* __restrict__ c1,
        const float* __restrict__ timev,
        const float* __restrict__ rope_w,
        unsigned short* __restrict__ Qr,
        unsigned short* __restrict__ Kr,
        unsigned short* __restrict__ Vt) {
    int s = blockIdx.x, b = blockIdx.y;
    int i = threadIdx.x;
    int m = b * S_LEN + s;
    float t = timev[m];
    float inv = powf(10000.f, -(float)i / 64.f);
    float w = rope_w[i];
    float f = t * inv * w;
    float cs = cosf(f), sn = sinf(f);

    #pragma unroll
    for (int h = 0; h < NH; h++) {
        int base = m * 3072 + h * 128;
        float x1 = b2f(c1[base + i]), x2 = b2f(c1[base + 64 + i]);
        int ob = ((b * NH + h) * S_LEN + s) * 128;
        Qr[ob + i]      = f2bf(x1 * cs - x2 * sn);
        Qr[ob + 64 + i] = f2bf(x2 * cs + x1 * sn);
    }
    #pragma unroll
    for (int h = 0; h < NKV; h++) {
        int base = m * 3072 + 2048 + h * 128;
        float x1 = b2f(c1[base + i]), x2 = b2f(c1[base + 64 + i]);
        int ob = ((b * NKV + h) * S_LEN + s) * 128;
        Kr[ob + i]      = f2bf(x1 * cs - x2 * sn);
        Kr[ob + 64 + i] = f2bf(x2 * cs + x1 * sn);
        int vbase = m * 3072 + 2560 + h * 128;
        int vtb = (b * NKV + h) * 128 * S_LEN;
        Vt[vtb + i * S_LEN + s]        = c1[vbase + i];
        Vt[vtb + (64 + i) * S_LEN + s] = c1[vbase + 64 + i];
    }
}

// ---------------------------------------------------------------------------
// Causal flash attention, GQA, TRANSPOSED scores.  Grid (NH, 16, B), 512 thr.
// Wave w owns q rows qw..qw+15 (qw = qt*128 + w*16); each lane owns ONE q row
// (q = qw + l16) -> softmax state m,l,alpha are per-lane scalars; reductions
// are local-reg + shfl_xor(16,32).  S^T = mfma(kf, qf); O^T = mfma(vf, pf).
// K/V staged via XOR-swizzled global_load_lds (no pad, conflict-free b128).
// __launch_bounds__(512,4): cap 128 regs/wave -> 2 blocks/CU co-resident.
// ---------------------------------------------------------------------------
__global__ __launch_bounds__(512, 4) void attn_kernel(
        const unsigned short* __restrict__ Qr,
        const unsigned short* __restrict__ Kr,
        const unsigned short* __restrict__ Vt,
        unsigned short* __restrict__ Out) {
    __shared__ __align__(16) unsigned short Ks[64 * 128];   // swizzled chunks
    __shared__ __align__(16) unsigned short Vs[128 * 64];   // swizzled chunks
    __shared__ __align__(16) unsigned short Ps[8][16 * 66]; // P^T stored [q][kv]

    const int h = blockIdx.x, b = blockIdx.z;
    const int qt = b ? blockIdx.y : (int)(gridDim.y - 1 - blockIdx.y);
    const int tid = threadIdx.x, w = tid >> 6, lane = tid & 63;
    const int quad = lane >> 4, l16 = lane & 15;
    const int hk = h >> 2;
    const unsigned short* Qb = Qr + (long)((b * NH + h) * S_LEN) * HD;
    const unsigned short* Kb = Kr + (long)((b * NKV + hk) * S_LEN) * HD;
    const unsigned short* Vb = Vt + (long)((b * NKV + hk) * HD) * S_LEN;
    const int qw = qt * 128 + w * 16;
    const int q  = qw + l16;                 // this lane's q row
    const float sl2 = 0.08838834764831845f * 1.4426950408889634f;
    const float MASK_MIN = -3.0e38f;

    // Q fragment (B-operand): B[k=hd][n=q], n=l16 -> row q, k=quad*8+j
    bf16x8 qf[4];
    #pragma unroll
    for (int kc = 0; kc < 4; kc++)
        qf[kc] = *(const bf16x8*)&Qb[(long)q * HD + kc * 32 + quad * 8];

    // O^T accumulator: D[m=d][n=q]; lane: q=l16 col, rows d=db*16+quad*4+r
    f32x4 o[8];
    #pragma unroll
    for (int db = 0; db < 8; db++)
        #pragma unroll
        for (int c = 0; c < 4; c++) o[db][c] = 0.f;
    float mr = MASK_MIN, lr = 0.f;

    // staging slots (thread-invariant parts)
    const int sK0 = tid, sK1 = tid + 512;
    const int kR0 = sK0 >> 4, kC0 = ((sK0 & 15) ^ (kR0 & 15)) * 8;
    const int kR1 = sK1 >> 4, kC1 = ((sK1 & 15) ^ (kR1 & 15)) * 8;
    const int vR0 = sK0 >> 3, vC0 = ((sK0 & 7) ^ (vR0 & 7)) * 8;
    const int vR1 = sK1 >> 3, vC1 = ((sK1 & 7) ^ (vR1 & 7)) * 8;

    const int nkt = 2 * qt + 2;
    for (int kt = 0; kt < nkt; kt++) {
        const int k0 = kt * 64;
        __syncthreads();    // prior tile's LDS reads done before overwrite
        gload_lds16(&Kb[(long)(k0 + kR0) * HD + kC0], &Ks[sK0 * 8]);
        gload_lds16(&Kb[(long)(k0 + kR1) * HD + kC1], &Ks[sK1 * 8]);
        gload_lds16(&Vb[(long)vR0 * S_LEN + k0 + vC0], &Vs[sK0 * 8]);
        gload_lds16(&Vb[(long)vR1 * S_LEN + k0 + vC1], &Vs[sK1 * 8]);
        __syncthreads();    // implicit vmcnt(0): staged data visible

        if (k0 > qw + 15) continue;          // fully masked for this wave

        // ---- S^T tiles: sc[nb] rows kv=k0+nb*16+quad*4+r, col q ----
        f32x4 sc[4];
        #pragma unroll
        for (int nb = 0; nb < 4; nb++) {
            #pragma unroll
            for (int c = 0; c < 4; c++) sc[nb][c] = 0.f;
            #pragma unroll
            for (int kc = 0; kc < 4; kc++) {
                bf16x8 kf = *(const bf16x8*)
                    &Ks[(nb * 16 + l16) * 128 + (((kc * 4 + quad) ^ l16) * 8)];
                sc[nb] = __builtin_amdgcn_mfma_f32_16x16x32_bf16(kf, qf[kc], sc[nb], 0, 0, 0);
            }
        }
        // ---- scale + causal mask (kv > q) ----
        if (k0 + 63 > qw) {                  // diagonal region
            #pragma unroll
            for (int nb = 0; nb < 4; nb++) {
                int kvb = k0 + nb * 16 + quad * 4;
                #pragma unroll
                for (int r = 0; r < 4; r++) {
                    float v = sc[nb][r] * sl2;
                    sc[nb][r] = (kvb + r > q) ? MASK_MIN : v;
                }
            }
        } else {
            #pragma unroll
            for (int nb = 0; nb < 4; nb++)
                #pragma unroll
                for (int r = 0; r < 4; r++) sc[nb][r] *= sl2;
        }
        // ---- per-lane online softmax over 64 kv (16 regs x 4 quads) ----
        float tm = MASK_MIN;
        #pragma unroll
        for (int nb = 0; nb < 4; nb++)
            #pragma unroll
            for (int r = 0; r < 4; r++) tm = fmaxf(tm, sc[nb][r]);
        tm = fmaxf(tm, __shfl_xor(tm, 16));
        tm = fmaxf(tm, __shfl_xor(tm, 32));
        float mn = fmaxf(mr, tm);
        float alpha = exp2f(mr - mn);
        mr = mn;
        float rs = 0.f;
        #pragma unroll
        for (int nb = 0; nb < 4; nb++)
            #pragma unroll
            for (int r = 0; r < 4; r++) {
                float pv = exp2f(sc[nb][r] - mn);
                rs += pv;
                Ps[w][l16 * 66 + nb * 16 + quad * 4 + r] = f2bf(pv);
            }
        rs += __shfl_xor(rs, 16);
        rs += __shfl_xor(rs, 32);
        lr = lr * alpha + rs;
        #pragma unroll
        for (int db = 0; db < 8; db++)
            #pragma unroll
            for (int c = 0; c < 4; c++) o[db][c] *= alpha;
        // (Ps[w] private to wave w: lgkmcnt orders write->read, no barrier)

        // ---- O^T += V^T P^T : mfma(vf, pf) ----
        #pragma unroll
        for (int kk = 0; kk < 2; kk++) {
            bf16x8 pf = *(const bf16x8*)&Ps[w][l16 * 66 + kk * 32 + quad * 8];
            #pragma unroll
            for (int db = 0; db < 8; db++) {
                bf16x8 vf = *(const bf16x8*)
                    &Vs[(db * 16 + l16) * 64 + (((kk * 4 + quad) ^ (l16 & 7)) * 8)];
                o[db] = __builtin_amdgcn_mfma_f32_16x16x32_bf16(vf, pf, o[db], 0, 0, 0);
            }
        }
    }

    // ---- epilogue: lane writes its q row; 4 bf16 packed per 8B store ----
    float inv_l = 1.0f / lr;
    long obase = (long)(b * S_LEN + q) * 2048 + h * 128 + quad * 4;
    #pragma unroll
    for (int db = 0; db < 8; db++) {
        u32x2 pk;
        pk.x = (unsigned)f2bf(o[db][0] * inv_l) | ((unsigned)f2bf(o[db][1] * inv_l) << 16);
        pk.y = (unsigned)f2bf(o[db][2] * inv_l) | ((unsigned)f2bf(o[db][3] * inv_l) << 16);
        *(u32x2*)&Out[obase + db * 16] = pk;
    }
}

// ---------------------------------------------------------------------------
extern "C" void kernel_launch(void* const* d_in, const int* in_sizes, int n_in,
                              void* d_out, int out_size, void* d_ws, size_t ws_size,
                              hipStream_t stream) {
    const float* X  = (const float*)d_in[0];
    const float* tv = (const float*)d_in[1];
    const float* wq = (const float*)d_in[2];
    const float* bq = (const float*)d_in[3];
    const float* wk = (const float*)d_in[4];
    const float* bk = (const float*)d_in[5];
    const float* wv = (const float*)d_in[6];
    const float* bv = (const float*)d_in[7];
    const float* wo = (const float*)d_in[8];
    const float* rw = (const float*)d_in[9];

    char* ws = (char*)d_ws;
    unsigned short* Wt  = (unsigned short*)ws; ws += 3072L * 2048 * 2;
    float*          bsf = (float*)ws;          ws += 3072L * 4;
    unsigned short* C1  = (unsigned short*)ws; ws += 4096L * 3072 * 2;
    unsigned short* Qr  = (unsigned short*)ws; ws += (long)BATCH * NH  * S_LEN * 128 * 2;
    unsigned short* Kr  = (unsigned short*)ws; ws += (long)BATCH * NKV * S_LEN * 128 * 2;
    unsigned short* Vt  = (unsigned short*)ws; ws += (long)BATCH * NKV * 128 * S_LEN * 2;
    unsigned short* Xb  = Qr;   // alias: Xb dead before rope writes Qr
    unsigned short* AO  = C1;   // alias: C1 dead after rope

    dim3 tb(32, 8);
    f32_to_bf16_kernel<<<4096, 256, 0, stream>>>(X, Xb, 4096L * 2048);
    transpose_to_bf16<<<dim3(64, 64), tb, 0, stream>>>(wq, Wt, 2048, 2048, 0L, 2048);
    transpose_to_bf16<<<dim3(16, 64), tb, 0, stream>>>(wk, Wt, 2048, 512, 2048L * 2048, 2048);
    transpose_to_bf16<<<dim3(16, 64), tb, 0, stream>>>(wv, Wt, 2048, 512, 2560L * 2048, 2048);
    bias_concat<<<12, 256, 0, stream>>>(bq, bk, bv, bsf);

    gemm_bt_async<unsigned short><<<dim3(24, 32), 256, 0, stream>>>(
        Xb, Wt, C1, bsf, 2048, 2048, 2048, 3072);
    rope_kernel<<<dim3(S_LEN, BATCH), 64, 0, stream>>>(C1, tv, rw, Qr, Kr, Vt);
    transpose_to_bf16<<<dim3(64, 64), tb, 0, stream>>>(wo, Wt, 2048, 2048, 0L, 2048);
    attn_kernel<<<dim3(NH, S_LEN / 128, BATCH), 512, 0, stream>>>(Qr, Kr, Vt, AO);
    gemm_bt_async<float><<<dim3(16, 32), 256, 0, stream>>>(
        AO, Wt, (float*)d_out, nullptr, 2048, 2048, 2048, 2048);
}

// Round 7
// 353.865 us; speedup vs baseline: 1.3502x; 1.0102x over previous
//
#include <hip/hip_runtime.h>

// ---------------------------------------------------------------------------
// TimeMoeAttention: X@Wq/Wk/Wv + bias -> continuous-time RoPE -> causal GQA
// attention -> @Wo.  B=2, S=2048, H=2048, NH=16, NKV=4, HD=128.
// I/O fp32; internal bf16 + fp32 MFMA accumulation.
// R7: RoPE fused into gemm1 epilogue (C1 + rope kernel eliminated; cos/sin
//     precomputed table), attn Ps stores packed 4x, prep kernels fused.
//     6 launches total.
// ---------------------------------------------------------------------------

#define S_LEN 2048
#define BATCH 2
#define NH    16
#define NKV   4
#define HD    128

typedef float  f32x4  __attribute__((ext_vector_type(4)));
typedef __bf16 bf16x8 __attribute__((ext_vector_type(8)));
typedef unsigned int u32x4 __attribute__((ext_vector_type(4)));
typedef unsigned int u32x2 __attribute__((ext_vector_type(2)));

__device__ inline unsigned short f2bf(float f) {
    unsigned u = __builtin_bit_cast(unsigned, f);
    unsigned r = (u + 0x7fffu + ((u >> 16) & 1u)) >> 16;   // RNE
    return (unsigned short)r;
}

// async global->LDS, 16 bytes per lane
__device__ inline void gload_lds16(const void* g, void* l) {
    __builtin_amdgcn_global_load_lds(
        (const __attribute__((address_space(1))) unsigned int*)g,
        (__attribute__((address_space(3))) unsigned int*)l, 16, 0, 0);
}

// ---------------------------------------------------------------------------
// Fused transposes: wq|wk|wv (fp32) -> Wt (bf16, [3072][2048]).  z selects.
// ---------------------------------------------------------------------------
__global__ void transpose_qkv(const float* __restrict__ wq,
                              const float* __restrict__ wk,
                              const float* __restrict__ wv,
                              unsigned short* __restrict__ Wt) {
    int z = blockIdx.z;
    const float* src = (z == 0) ? wq : ((z == 1) ? wk : wv);
    int C = (z == 0) ? 2048 : 512;
    long doff = (z == 0) ? 0L : ((z == 1) ? 2048L * 2048 : 2560L * 2048);
    int bx = blockIdx.x * 32, by = blockIdx.y * 32;
    if (bx >= C) return;
    __shared__ unsigned short t[32][33];
    int x = threadIdx.x, y0 = threadIdx.y;
    #pragma unroll
    for (int i = 0; i < 4; i++) {
        int y = y0 + i * 8;
        t[y][x] = f2bf(src[(long)(by + y) * C + bx + x]);
    }
    __syncthreads();
    #pragma unroll
    for (int i = 0; i < 4; i++) {
        int y = y0 + i * 8;
        Wt[doff + (long)(bx + y) * 2048 + by + x] = t[x][y];
    }
}

// single fp32->bf16 transpose (for wo, launched after gemm1 frees Wt)
__global__ void transpose_to_bf16(const float* __restrict__ src,
                                  unsigned short* __restrict__ dst,
                                  int R, int C, long dst_off, int ldd) {
    __shared__ unsigned short t[32][33];
    int bx = blockIdx.x * 32, by = blockIdx.y * 32;
    int x = threadIdx.x, y0 = threadIdx.y;
    #pragma unroll
    for (int i = 0; i < 4; i++) {
        int y = y0 + i * 8;
        t[y][x] = f2bf(src[(long)(by + y) * C + bx + x]);
    }
    __syncthreads();
    #pragma unroll
    for (int i = 0; i < 4; i++) {
        int y = y0 + i * 8;
        dst[dst_off + (long)(bx + y) * ldd + by + x] = t[x][y];
    }
}

// ---------------------------------------------------------------------------
// Prep: X fp32->bf16 (all 4096 blocks), bias concat (blocks 0-11),
// cos/sin table [4096 tokens][64 freqs] fp32 (blocks 0-1023).
// ---------------------------------------------------------------------------
__global__ __launch_bounds__(256) void prep_kernel(
        const float* __restrict__ X, unsigned short* __restrict__ Xb,
        const float* __restrict__ bq, const float* __restrict__ bk,
        const float* __restrict__ bv, float* __restrict__ bsf,
        const float* __restrict__ tv, const float* __restrict__ rw,
        float* __restrict__ Cs, float* __restrict__ Sn) {
    int bi = blockIdx.x, tid = threadIdx.x;
    long i = ((long)bi * 256 + tid) * 8;
    {
        f32x4 a = *(const f32x4*)&X[i];
        f32x4 b = *(const f32x4*)&X[i + 4];
        u32x4 r;
        r.x = (unsigned)f2bf(a[0]) | ((unsigned)f2bf(a[1]) << 16);
        r.y = (unsigned)f2bf(a[2]) | ((unsigned)f2bf(a[3]) << 16);
        r.z = (unsigned)f2bf(b[0]) | ((unsigned)f2bf(b[1]) << 16);
        r.w = (unsigned)f2bf(b[2]) | ((unsigned)f2bf(b[3]) << 16);
        *(u32x4*)&Xb[i] = r;
    }
    if (bi < 12) {
        int ib = bi * 256 + tid;
        bsf[ib] = (ib < 2048) ? bq[ib] : ((ib < 2560) ? bk[ib - 2048] : bv[ib - 2560]);
    }
    if (bi < 1024) {
        int m = bi * 4 + (tid >> 6);
        int fi = tid & 63;
        float t = tv[m];
        float f = t * powf(10000.f, -(float)fi / 64.f) * rw[fi];
        Cs[m * 64 + fi] = cosf(f);
        Sn[m * 64 + fi] = sinf(f);
    }
}

// ---------------------------------------------------------------------------
// GEMM1 + bias + RoPE fused.  A=Xb bf16 [4096][2048], Bt=Wt bf16 [3072][2048].
// Grid (24,32): bx 0..15 -> Q head bx; 16..19 -> K head bx-16; 20..23 -> V.
// K-loop = m97 structure.  Epilogue: per-mi chunk (32 rows x 128 cols fp32)
// through LDS; Q/K: bias+rope -> Qr/Kr; V: bias + transpose -> Vt.
// ---------------------------------------------------------------------------
__global__ __launch_bounds__(256) void gemm_qkv_rope(
        const unsigned short* __restrict__ A,
        const unsigned short* __restrict__ Bt,
        const float* __restrict__ bsf,
        const float* __restrict__ Cs, const float* __restrict__ Sn,
        unsigned short* __restrict__ Qr,
        unsigned short* __restrict__ Kr,
        unsigned short* __restrict__ Vt) {
    __shared__ __align__(16) char smem[32 * 132 * 4];   // 16896 B
    unsigned short* As = (unsigned short*)smem;          // 8192 B
    unsigned short* Bs = (unsigned short*)(smem + 8192); // 8192 B
    float* Ep = (float*)smem;                            // epilogue: 32x132 fp32

    const int tid = threadIdx.x;
    const int wid = tid >> 6, lane = tid & 63, quad = lane >> 4, l16 = lane & 15;
    const int wr = wid >> 1, wc = wid & 1;
    const int m0 = blockIdx.y * 128, n0 = blockIdx.x * 128;
    const int bx = blockIdx.x;

    const int cA = tid, cB = 256 + tid;
    const int rowA = cA >> 2, colA = (cA & 3) * 8;
    const int rowB = cB >> 2, colB = (cB & 3) * 8;

    f32x4 acc[4][4];
    #pragma unroll
    for (int i = 0; i < 4; i++)
        #pragma unroll
        for (int j = 0; j < 4; j++)
            #pragma unroll
            for (int c = 0; c < 4; c++) acc[i][j][c] = 0.f;

    for (int k0 = 0; k0 < 2048; k0 += 32) {
        gload_lds16(&A[(long)(m0 + rowA) * 2048 + k0 + colA], &As[cA * 8]);
        gload_lds16(&A[(long)(m0 + rowB) * 2048 + k0 + colB], &As[cB * 8]);
        gload_lds16(&Bt[(long)(n0 + rowA) * 2048 + k0 + colA], &Bs[cA * 8]);
        gload_lds16(&Bt[(long)(n0 + rowB) * 2048 + k0 + colB], &Bs[cB * 8]);
        __syncthreads();
        bf16x8 af[4], bfr[4];
        #pragma unroll
        for (int mi = 0; mi < 4; mi++)
            af[mi] = *(const bf16x8*)&As[(wr * 64 + mi * 16 + l16) * 32 + quad * 8];
        #pragma unroll
        for (int ni = 0; ni < 4; ni++)
            bfr[ni] = *(const bf16x8*)&Bs[(wc * 64 + ni * 16 + l16) * 32 + quad * 8];
        #pragma unroll
        for (int mi = 0; mi < 4; mi++)
            #pragma unroll
            for (int ni = 0; ni < 4; ni++)
                acc[mi][ni] = __builtin_amdgcn_mfma_f32_16x16x32_bf16(
                    af[mi], bfr[ni], acc[mi][ni], 0, 0, 0);
        __syncthreads();
    }

    // ---- fused epilogue ----
    float bv4[4];
    #pragma unroll
    for (int ni = 0; ni < 4; ni++) bv4[ni] = bsf[n0 + wc * 64 + ni * 16 + l16];
    const bool isV = (bx >= 20);

    #pragma unroll
    for (int mi = 0; mi < 4; mi++) {
        // phase1: acc + bias -> Ep[e][col], e = wr*16+quad*4+r
        #pragma unroll
        for (int ni = 0; ni < 4; ni++)
            #pragma unroll
            for (int r = 0; r < 4; r++)
                Ep[(wr * 16 + quad * 4 + r) * 132 + wc * 64 + ni * 16 + l16] =
                    acc[mi][ni][r] + bv4[ni];
        __syncthreads();
        if (!isV) {
            // rope + store: thread = (row lr 0..31, col-octet jj 0..7)
            const int lr = tid >> 3, jj = tid & 7, j0 = jj * 8;
            const int gm = m0 + ((lr >> 4) << 6) + mi * 16 + (lr & 15);
            const int bb = gm >> 11, s = gm & 2047;
            unsigned short* dst = (bx < 16)
                ? Qr + ((long)(bb * NH + bx) * S_LEN + s) * HD
                : Kr + ((long)(bb * NKV + (bx - 16)) * S_LEN + s) * HD;
            f32x4 x1a = *(f32x4*)&Ep[lr * 132 + j0];
            f32x4 x1b = *(f32x4*)&Ep[lr * 132 + j0 + 4];
            f32x4 x2a = *(f32x4*)&Ep[lr * 132 + 64 + j0];
            f32x4 x2b = *(f32x4*)&Ep[lr * 132 + 64 + j0 + 4];
            f32x4 ca = *(const f32x4*)&Cs[(long)gm * 64 + j0];
            f32x4 cb = *(const f32x4*)&Cs[(long)gm * 64 + j0 + 4];
            f32x4 sa = *(const f32x4*)&Sn[(long)gm * 64 + j0];
            f32x4 sb = *(const f32x4*)&Sn[(long)gm * 64 + j0 + 4];
            f32x4 la, lb, ha, hb;
            #pragma unroll
            for (int e = 0; e < 4; e++) {
                la[e] = x1a[e] * ca[e] - x2a[e] * sa[e];
                ha[e] = x2a[e] * ca[e] + x1a[e] * sa[e];
                lb[e] = x1b[e] * cb[e] - x2b[e] * sb[e];
                hb[e] = x2b[e] * cb[e] + x1b[e] * sb[e];
            }
            u32x4 lo, hi;
            lo.x = (unsigned)f2bf(la[0]) | ((unsigned)f2bf(la[1]) << 16);
            lo.y = (unsigned)f2bf(la[2]) | ((unsigned)f2bf(la[3]) << 16);
            lo.z = (unsigned)f2bf(lb[0]) | ((unsigned)f2bf(lb[1]) << 16);
            lo.w = (unsigned)f2bf(lb[2]) | ((unsigned)f2bf(lb[3]) << 16);
            hi.x = (unsigned)f2bf(ha[0]) | ((unsigned)f2bf(ha[1]) << 16);
            hi.y = (unsigned)f2bf(ha[2]) | ((unsigned)f2bf(ha[3]) << 16);
            hi.z = (unsigned)f2bf(hb[0]) | ((unsigned)f2bf(hb[1]) << 16);
            hi.w = (unsigned)f2bf(hb[2]) | ((unsigned)f2bf(hb[3]) << 16);
            *(u32x4*)&dst[j0] = lo;
            *(u32x4*)&dst[64 + j0] = hi;
        } else {
            // V: bias only, transposed store Vt[d][s] (16 contiguous s / thread)
            const int d = tid >> 1, sh = tid & 1;
            const int gmb = m0 + sh * 64 + mi * 16;
            const int bb = gmb >> 11, s0 = gmb & 2047;
            unsigned short* dst =
                Vt + ((long)(bb * NKV + (bx - 20)) * HD + d) * S_LEN + s0;
            unsigned short pv[16];
            #pragma unroll
            for (int t = 0; t < 16; t++)
                pv[t] = f2bf(Ep[(sh * 16 + t) * 132 + d]);
            u32x4 v0, v1;
            v0.x = (unsigned)pv[0]  | ((unsigned)pv[1]  << 16);
            v0.y = (unsigned)pv[2]  | ((unsigned)pv[3]  << 16);
            v0.z = (unsigned)pv[4]  | ((unsigned)pv[5]  << 16);
            v0.w = (unsigned)pv[6]  | ((unsigned)pv[7]  << 16);
            v1.x = (unsigned)pv[8]  | ((unsigned)pv[9]  << 16);
            v1.y = (unsigned)pv[10] | ((unsigned)pv[11] << 16);
            v1.z = (unsigned)pv[12] | ((unsigned)pv[13] << 16);
            v1.w = (unsigned)pv[14] | ((unsigned)pv[15] << 16);
            *(u32x4*)&dst[0] = v0;
            *(u32x4*)&dst[8] = v1;
        }
        __syncthreads();   // before next chunk overwrites Ep
    }
}

// ---------------------------------------------------------------------------
// GEMM2 (plain epilogue): C fp32 = AO bf16 x Wt^T (+0).
// ---------------------------------------------------------------------------
template <typename CT>
__global__ __launch_bounds__(256) void gemm_bt_async(
        const unsigned short* __restrict__ A,
        const unsigned short* __restrict__ Bt,
        CT* __restrict__ C,
        const float* __restrict__ bias,
        int K, int lda, int ldb, int ldc) {
    __shared__ __align__(16) unsigned short As[128 * 32];
    __shared__ __align__(16) unsigned short Bs[128 * 32];
    const int tid = threadIdx.x;
    const int wid = tid >> 6, lane = tid & 63, quad = lane >> 4, l16 = lane & 15;
    const int wr = wid >> 1, wc = wid & 1;
    const int m0 = blockIdx.y * 128, n0 = blockIdx.x * 128;

    const int cA = tid, cB = 256 + tid;
    const int rowA = cA >> 2, colA = (cA & 3) * 8;
    const int rowB = cB >> 2, colB = (cB & 3) * 8;

    f32x4 acc[4][4];
    #pragma unroll
    for (int i = 0; i < 4; i++)
        #pragma unroll
        for (int j = 0; j < 4; j++)
            #pragma unroll
            for (int c = 0; c < 4; c++) acc[i][j][c] = 0.f;

    for (int k0 = 0; k0 < K; k0 += 32) {
        gload_lds16(&A[(long)(m0 + rowA) * lda + k0 + colA], &As[cA * 8]);
        gload_lds16(&A[(long)(m0 + rowB) * lda + k0 + colB], &As[cB * 8]);
        gload_lds16(&Bt[(long)(n0 + rowA) * ldb + k0 + colA], &Bs[cA * 8]);
        gload_lds16(&Bt[(long)(n0 + rowB) * ldb + k0 + colB], &Bs[cB * 8]);
        __syncthreads();
        bf16x8 af[4], bfr[4];
        #pragma unroll
        for (int mi = 0; mi < 4; mi++)
            af[mi] = *(const bf16x8*)&As[(wr * 64 + mi * 16 + l16) * 32 + quad * 8];
        #pragma unroll
        for (int ni = 0; ni < 4; ni++)
            bfr[ni] = *(const bf16x8*)&Bs[(wc * 64 + ni * 16 + l16) * 32 + quad * 8];
        #pragma unroll
        for (int mi = 0; mi < 4; mi++)
            #pragma unroll
            for (int ni = 0; ni < 4; ni++)
                acc[mi][ni] = __builtin_amdgcn_mfma_f32_16x16x32_bf16(
                    af[mi], bfr[ni], acc[mi][ni], 0, 0, 0);
        __syncthreads();
    }

    #pragma unroll
    for (int mi = 0; mi < 4; mi++) {
        #pragma unroll
        for (int ni = 0; ni < 4; ni++) {
            int gn = n0 + wc * 64 + ni * 16 + l16;
            float bv_ = bias ? bias[gn] : 0.f;
            #pragma unroll
            for (int r = 0; r < 4; r++) {
                int gm = m0 + wr * 64 + mi * 16 + quad * 4 + r;
                float v = acc[mi][ni][r] + bv_;
                if constexpr (sizeof(CT) == 4) C[(long)gm * ldc + gn] = v;
                else                           C[(long)gm * ldc + gn] = f2bf(v);
            }
        }
    }
}

// ---------------------------------------------------------------------------
// Causal flash attention, GQA, transposed scores (R6 structure).
// R7: Ps stores packed 4 bf16 -> 8B (stride 68 for 8B alignment).
// ---------------------------------------------------------------------------
__global__ __launch_bounds__(512, 4) void attn_kernel(
        const unsigned short* __restrict__ Qr,
        const unsigned short* __restrict__ Kr,
        const unsigned short* __restrict__ Vt,
        unsigned short* __restrict__ Out) {
    __shared__ __align__(16) unsigned short Ks[64 * 128];
    __shared__ __align__(16) unsigned short Vs[128 * 64];
    __shared__ __align__(16) unsigned short Ps[8][16 * 68];

    const int h = blockIdx.x, b = blockIdx.z;
    const int qt = b ? blockIdx.y : (int)(gridDim.y - 1 - blockIdx.y);
    const int tid = threadIdx.x, w = tid >> 6, lane = tid & 63;
    const int quad = lane >> 4, l16 = lane & 15;
    const int hk = h >> 2;
    const unsigned short* Qb = Qr + (long)((b * NH + h) * S_LEN) * HD;
    const unsigned short* Kb = Kr + (long)((b * NKV + hk) * S_LEN) * HD;
    const unsigned short* Vb = Vt + (long)((b * NKV + hk) * HD) * S_LEN;
    const int qw = qt * 128 + w * 16;
    const int q  = qw + l16;
    const float sl2 = 0.08838834764831845f * 1.4426950408889634f;
    const float MASK_MIN = -3.0e38f;

    bf16x8 qf[4];
    #pragma unroll
    for (int kc = 0; kc < 4; kc++)
        qf[kc] = *(const bf16x8*)&Qb[(long)q * HD + kc * 32 + quad * 8];

    f32x4 o[8];
    #pragma unroll
    for (int db = 0; db < 8; db++)
        #pragma unroll
        for (int c = 0; c < 4; c++) o[db][c] = 0.f;
    float mr = MASK_MIN, lr = 0.f;

    const int sK0 = tid, sK1 = tid + 512;
    const int kR0 = sK0 >> 4, kC0 = ((sK0 & 15) ^ (kR0 & 15)) * 8;
    const int kR1 = sK1 >> 4, kC1 = ((sK1 & 15) ^ (kR1 & 15)) * 8;
    const int vR0 = sK0 >> 3, vC0 = ((sK0 & 7) ^ (vR0 & 7)) * 8;
    const int vR1 = sK1 >> 3, vC1 = ((sK1 & 7) ^ (vR1 & 7)) * 8;

    const int nkt = 2 * qt + 2;
    for (int kt = 0; kt < nkt; kt++) {
        const int k0 = kt * 64;
        __syncthreads();
        gload_lds16(&Kb[(long)(k0 + kR0) * HD + kC0], &Ks[sK0 * 8]);
        gload_lds16(&Kb[(long)(k0 + kR1) * HD + kC1], &Ks[sK1 * 8]);
        gload_lds16(&Vb[(long)vR0 * S_LEN + k0 + vC0], &Vs[sK0 * 8]);
        gload_lds16(&Vb[(long)vR1 * S_LEN + k0 + vC1], &Vs[sK1 * 8]);
        __syncthreads();

        if (k0 > qw + 15) continue;

        f32x4 sc[4];
        #pragma unroll
        for (int nb = 0; nb < 4; nb++) {
            #pragma unroll
            for (int c = 0; c < 4; c++) sc[nb][c] = 0.f;
            #pragma unroll
            for (int kc = 0; kc < 4; kc++) {
                bf16x8 kf = *(const bf16x8*)
                    &Ks[(nb * 16 + l16) * 128 + (((kc * 4 + quad) ^ l16) * 8)];
                sc[nb] = __builtin_amdgcn_mfma_f32_16x16x32_bf16(kf, qf[kc], sc[nb], 0, 0, 0);
            }
        }
        if (k0 + 63 > qw) {
            #pragma unroll
            for (int nb = 0; nb < 4; nb++) {
                int kvb = k0 + nb * 16 + quad * 4;
                #pragma unroll
                for (int r = 0; r < 4; r++) {
                    float v = sc[nb][r] * sl2;
                    sc[nb][r] = (kvb + r > q) ? MASK_MIN : v;
                }
            }
        } else {
            #pragma unroll
            for (int nb = 0; nb < 4; nb++)
                #pragma unroll
                for (int r = 0; r < 4; r++) sc[nb][r] *= sl2;
        }
        float tm = MASK_MIN;
        #pragma unroll
        for (int nb = 0; nb < 4; nb++)
            #pragma unroll
            for (int r = 0; r < 4; r++) tm = fmaxf(tm, sc[nb][r]);
        tm = fmaxf(tm, __shfl_xor(tm, 16));
        tm = fmaxf(tm, __shfl_xor(tm, 32));
        float mn = fmaxf(mr, tm);
        float alpha = exp2f(mr - mn);
        mr = mn;
        float rs = 0.f;
        #pragma unroll
        for (int nb = 0; nb < 4; nb++) {
            float pv0 = exp2f(sc[nb][0] - mn), pv1 = exp2f(sc[nb][1] - mn);
            float pv2 = exp2f(sc[nb][2] - mn), pv3 = exp2f(sc[nb][3] - mn);
            rs += (pv0 + pv1) + (pv2 + pv3);
            u32x2 pk;
            pk.x = (unsigned)f2bf(pv0) | ((unsigned)f2bf(pv1) << 16);
            pk.y = (unsigned)f2bf(pv2) | ((unsigned)f2bf(pv3) << 16);
            *(u32x2*)&Ps[w][l16 * 68 + nb * 16 + quad * 4] = pk;
        }
        rs += __shfl_xor(rs, 16);
        rs += __shfl_xor(rs, 32);
        lr = lr * alpha + rs;
        #pragma unroll
        for (int db = 0; db < 8; db++)
            #pragma unroll
            for (int c = 0; c < 4; c++) o[db][c] *= alpha;

        #pragma unroll
        for (int kk = 0; kk < 2; kk++) {
            bf16x8 pf = *(const bf16x8*)&Ps[w][l16 * 68 + kk * 32 + quad * 8];
            #pragma unroll
            for (int db = 0; db < 8; db++) {
                bf16x8 vf = *(const bf16x8*)
                    &Vs[(db * 16 + l16) * 64 + (((kk * 4 + quad) ^ (l16 & 7)) * 8)];
                o[db] = __builtin_amdgcn_mfma_f32_16x16x32_bf16(vf, pf, o[db], 0, 0, 0);
            }
        }
    }

    float inv_l = 1.0f / lr;
    long obase = (long)(b * S_LEN + q) * 2048 + h * 128 + quad * 4;
    #pragma unroll
    for (int db = 0; db < 8; db++) {
        u32x2 pk;
        pk.x = (unsigned)f2bf(o[db][0] * inv_l) | ((unsigned)f2bf(o[db][1] * inv_l) << 16);
        pk.y = (unsigned)f2bf(o[db][2] * inv_l) | ((unsigned)f2bf(o[db][3] * inv_l) << 16);
        *(u32x2*)&Out[obase + db * 16] = pk;
    }
}

// ---------------------------------------------------------------------------
extern "C" void kernel_launch(void* const* d_in, const int* in_sizes, int n_in,
                              void* d_out, int out_size, void* d_ws, size_t ws_size,
                              hipStream_t stream) {
    const float* X  = (const float*)d_in[0];
    const float* tv = (const float*)d_in[1];
    const float* wq = (const float*)d_in[2];
    const float* bq = (const float*)d_in[3];
    const float* wk = (const float*)d_in[4];
    const float* bk = (const float*)d_in[5];
    const float* wv = (const float*)d_in[6];
    const float* bv = (const float*)d_in[7];
    const float* wo = (const float*)d_in[8];
    const float* rw = (const float*)d_in[9];

    // Workspace (~57 MB):
    //   Wt 12.6MB ([wq|wk|wv]^T -> reused for wo^T after gemm1)
    //   bsf 12KB, Cs/Sn 2.1MB, Qr 16.8MB, Kr/Vt 8.4MB, AO 16.8MB (=Xb alias)
    char* ws = (char*)d_ws;
    unsigned short* Wt  = (unsigned short*)ws; ws += 3072L * 2048 * 2;
    float*          bsf = (float*)ws;          ws += 3072L * 4;
    float*          Cs  = (float*)ws;          ws += 4096L * 64 * 4;
    float*          Sn  = (float*)ws;          ws += 4096L * 64 * 4;
    unsigned short* Qr  = (unsigned short*)ws; ws += (long)BATCH * NH  * S_LEN * HD * 2;
    unsigned short* Kr  = (unsigned short*)ws; ws += (long)BATCH * NKV * S_LEN * HD * 2;
    unsigned short* Vt  = (unsigned short*)ws; ws += (long)BATCH * NKV * HD * S_LEN * 2;
    unsigned short* AO  = (unsigned short*)ws; ws += 4096L * 2048 * 2;
    unsigned short* Xb  = AO;   // alias: Xb dead (post-gemm1) before attn writes AO

    transpose_qkv<<<dim3(64, 64, 3), dim3(32, 8), 0, stream>>>(wq, wk, wv, Wt);
    prep_kernel<<<4096, 256, 0, stream>>>(X, Xb, bq, bk, bv, bsf, tv, rw, Cs, Sn);
    gemm_qkv_rope<<<dim3(24, 32), 256, 0, stream>>>(Xb, Wt, bsf, Cs, Sn, Qr, Kr, Vt);
    transpose_to_bf16<<<dim3(64, 64), dim3(32, 8), 0, stream>>>(wo, Wt, 2048, 2048, 0L, 2048);
    attn_kernel<<<dim3(NH, S_LEN / 128, BATCH), 512, 0, stream>>>(Qr, Kr, Vt, AO);
    gemm_bt_async<float><<<dim3(16, 32), 256, 0, stream>>>(
        AO, Wt, (float*)d_out, nullptr, 2048, 2048, 2048, 2048);
}